// Round 4
// baseline (413.114 us; speedup 1.0000x reference)
//
#include <hip/hip_runtime.h>
#include <hip/hip_bf16.h>
#include <cstdint>
#include <cstddef>

typedef __bf16 bf16_t;
typedef __bf16 bf16x8 __attribute__((ext_vector_type(8)));
typedef __bf16 bf16x4 __attribute__((ext_vector_type(4)));
typedef float  f32x4  __attribute__((ext_vector_type(4)));

#define M_DIM 16384   // B*S
#define N_DIM 3072    // 3*O
#define K_DIM 1024    // I
#define R_DIM 256
#define O_DIM 1024

// 256^2 8-phase geometry
#define BM 256
#define BN 256
#define BK 64
#define NTILE (N_DIM / BN)                    // 12
#define GRID_GEMM ((M_DIM / BM) * NTILE)      // 768
#define CHUNK_XCD (GRID_GEMM / 8)             // 96 (768 % 8 == 0 -> bijective)
#define SMEM_BYTES 131072

// LDS region map (bf16 elems): [c][A/B][kh] -> 256 rows x 32 k, 16 KB each.
#define REGN(c, isB, kh) ((c) * 32768 + (isB) * 16384 + (kh) * 8192)

__device__ __forceinline__ void gload_lds16(const bf16_t* g, bf16_t* l) {
  __builtin_amdgcn_global_load_lds(
      (__attribute__((address_space(1))) void*)(g),
      (__attribute__((address_space(3))) void*)(l), 16, 0, 0);
}

// ---------------------------------------------------------------------------
// prep: blocks [0,128): Q-rows fp32->bf16; [128,384): VeRA delta rows;
//       [384,8576): x fp32 -> bf16  (unchanged, verified rounds 0-3)
// ---------------------------------------------------------------------------
__global__ __launch_bounds__(256) void prep_all(
    const float* __restrict__ x,
    const float* __restrict__ base_w,
    const float* __restrict__ vA,
    const float* __restrict__ vB,
    const float* __restrict__ vd,
    const float* __restrict__ vb,
    bf16_t* __restrict__ Wf,
    bf16_t* __restrict__ xh)
{
  const int blk = blockIdx.x;
  const int t = threadIdx.x;

  if (blk >= 384) {
    const size_t base = ((size_t)(blk - 384) * 256 + t) * 8;
    const f32x4 v0 = *(const f32x4*)(x + base);
    const f32x4 v1 = *(const f32x4*)(x + base + 4);
    bf16x8 o;
    o[0] = (bf16_t)v0[0]; o[1] = (bf16_t)v0[1]; o[2] = (bf16_t)v0[2]; o[3] = (bf16_t)v0[3];
    o[4] = (bf16_t)v1[0]; o[5] = (bf16_t)v1[1]; o[6] = (bf16_t)v1[2]; o[7] = (bf16_t)v1[3];
    *(bf16x8*)(xh + base) = o;
    return;
  }

  if (blk < 128) {
    const float* src = base_w + (size_t)blk * 8 * K_DIM;
    bf16_t*      dst = Wf + (size_t)blk * 8 * K_DIM;
#pragma unroll
    for (int rr = 0; rr < 8; ++rr) {
      const f32x4 v = *(const f32x4*)(src + rr * K_DIM + t * 4);
      bf16x4 ov;
      ov[0] = (bf16_t)v[0]; ov[1] = (bf16_t)v[1];
      ov[2] = (bf16_t)v[2]; ov[3] = (bf16_t)v[3];
      *(bf16x4*)(dst + rr * K_DIM + t * 4) = ov;
    }
    return;
  }

  const int rb = (blk - 128) * 8;
  const int k  = rb >> 10;
  const int ob = rb & 1023;

  __shared__ float coeffT[R_DIM][8];
  {
    const int r = t;
    const float d = vd[k * R_DIM + r];
#pragma unroll
    for (int rr = 0; rr < 8; ++rr) {
      const int o = ob + rr;
      coeffT[r][rr] = vb[k * O_DIM + o] * vB[(size_t)o * R_DIM + r] * d;
    }
  }
  __syncthreads();

  float acc[8][4];
#pragma unroll
  for (int rr = 0; rr < 8; ++rr)
#pragma unroll
    for (int c = 0; c < 4; ++c) acc[rr][c] = 0.0f;

  for (int r = 0; r < R_DIM; ++r) {
    const f32x4 av = *(const f32x4*)(vA + (size_t)r * K_DIM + t * 4);
    const f32x4 c0 = *(const f32x4*)&coeffT[r][0];
    const f32x4 c1 = *(const f32x4*)&coeffT[r][4];
#pragma unroll
    for (int rr = 0; rr < 8; ++rr) {
      const float cc = (rr < 4) ? c0[rr] : c1[rr - 4];
      acc[rr][0] += cc * av[0];
      acc[rr][1] += cc * av[1];
      acc[rr][2] += cc * av[2];
      acc[rr][3] += cc * av[3];
    }
  }

#pragma unroll
  for (int rr = 0; rr < 8; ++rr) {
    const size_t row = (size_t)(1024 + rb + rr);
    const f32x4 bw = *(const f32x4*)(base_w + row * K_DIM + t * 4);
    bf16x4 ov;
    ov[0] = (bf16_t)(bw[0] + acc[rr][0]);
    ov[1] = (bf16_t)(bw[1] + acc[rr][1]);
    ov[2] = (bf16_t)(bw[2] + acc[rr][2]);
    ov[3] = (bf16_t)(bw[3] + acc[rr][3]);
    *(bf16x4*)(Wf + row * K_DIM + t * 4) = ov;
  }
}

// ---------------------------------------------------------------------------
// 256^2 8-phase GEMM, template-faithful phase structure (m201):
// per phase {ds-read regs; stage; [vmcnt]; barrier; lgkm; setprio+MFMA; barrier}
// ds_reads issued BEFORE the entry barrier (latency overlaps barrier wait);
// counted vmcnt(4) at p1 (confirms cur-tile kh1) and p3 (next-tile kh0),
// never 0 in the main loop. 8 barriers / K-tile = template rate.
// ---------------------------------------------------------------------------
__global__ __launch_bounds__(512, 2) void gemm_qkv(
    const bf16_t* __restrict__ Xh,    // (16384, 1024) bf16
    const bf16_t* __restrict__ W,     // (3072, 1024)  bf16 row-major (N,K)
    const float*  __restrict__ bias,  // (3072,) fp32
    float* __restrict__ out)          // (16384, 3072) fp32
{
  extern __shared__ __align__(16) bf16_t sm[];  // 128 KB dynamic

  const int rawbid = blockIdx.x;
  const int bid = (rawbid & 7) * CHUNK_XCD + (rawbid >> 3);
  const int mt = bid / NTILE, nt = bid % NTILE;
  const int m0 = mt * BM, n0 = nt * BN;

  const int t = threadIdx.x;
  const int lane = t & 63;
  const int w = t >> 6;          // 0..7
  const int wm = w >> 2;         // 0..1 (M half)
  const int wn = w & 3;          // 0..3 (N quarter)

  // staging: thread t loads rows (t>>2), (t>>2)+128; 16B at pre-swizzled
  // k-slot sig = (t&3) ^ ((t>>3)&3). LDS dest linear: elem 8t per region.
  const int srow = t >> 2;
  const int sig  = (t & 3) ^ ((t >> 3) & 3);
  const bf16_t* pA0 = Xh + (size_t)(m0 + srow) * K_DIM + sig * 8;
  const bf16_t* pA1 = pA0 + (size_t)128 * K_DIM;
  const bf16_t* pB0 = W  + (size_t)(n0 + srow) * K_DIM + sig * 8;
  const bf16_t* pB1 = pB0 + (size_t)128 * K_DIM;

  // fragment read offsets (elems, region-local), row stride 32 elems.
  // read slot = (lane>>4) ^ ((row>>1)&3): conflict-free (even bank spread).
  const int rA = wm * 128 + (lane & 15);
  const int rB = wn * 64  + (lane & 15);
  const int aoff = rA * 32 + (((lane >> 4) ^ ((rA >> 1) & 3)) * 8);
  const int boff = rB * 32 + (((lane >> 4) ^ ((rB >> 1) & 3)) * 8);

  f32x4 acc[8][4];
#pragma unroll
  for (int i = 0; i < 8; ++i)
#pragma unroll
    for (int j = 0; j < 4; ++j) acc[i][j] = (f32x4){0.f, 0.f, 0.f, 0.f};

#define STAGE(isB, c, kh, kb)                                              \
  do {                                                                     \
    const bf16_t* g0 = ((isB) ? pB0 : pA0) + (kb) + (kh) * 32;             \
    const bf16_t* g1 = ((isB) ? pB1 : pA1) + (kb) + (kh) * 32;             \
    bf16_t* l = sm + REGN(c, isB, kh) + w * 512;                           \
    gload_lds16(g0, l);                                                    \
    gload_lds16(g1, l + 4096);                                             \
  } while (0)

#define LOADA(c, kh)                                                       \
  {                                                                        \
    const bf16_t* base_ = sm + REGN(c, 0, kh) + aoff;                      \
    _Pragma("unroll") for (int i = 0; i < 8; ++i)                          \
        a[i] = *(const bf16x8*)(base_ + i * 512);                          \
  }

#define LOADB2(c, kh, j0)                                                  \
  {                                                                        \
    const bf16_t* base_ = sm + REGN(c, 1, kh) + boff;                      \
    b[j0]     = *(const bf16x8*)(base_ + (j0) * 512);                      \
    b[j0 + 1] = *(const bf16x8*)(base_ + ((j0) + 1) * 512);                \
  }

#define MFMA2(j0)                                                          \
  __builtin_amdgcn_s_setprio(1);                                           \
  _Pragma("unroll") for (int i = 0; i < 8; ++i) {                          \
    acc[i][j0] = __builtin_amdgcn_mfma_f32_16x16x32_bf16(                  \
        a[i], b[j0], acc[i][j0], 0, 0, 0);                                 \
    acc[i][(j0) + 1] = __builtin_amdgcn_mfma_f32_16x16x32_bf16(            \
        a[i], b[(j0) + 1], acc[i][(j0) + 1], 0, 0, 0);                     \
  }                                                                        \
  __builtin_amdgcn_s_setprio(0);

#define WAITV(n) asm volatile("s_waitcnt vmcnt(" #n ")" ::: "memory")
#define BARRIER()                                                          \
  __builtin_amdgcn_s_barrier();                                            \
  asm volatile("" ::: "memory")

  bf16x8 a[8], b[4];

  // prologue: stage tile 0 (units s0=A.kh0, s1=B.kh0, s2=A.kh1, s3=B.kh1)
  STAGE(0, 0, 0, 0);
  STAGE(1, 0, 0, 0);
  STAGE(0, 0, 1, 0);
  STAGE(1, 0, 1, 0);
  WAITV(4);     // retire s0,s1 -> kh0 of tile 0 complete (own wave)
  BARRIER();    // publish chip-wide; s2,s3 still in flight

  // main loop: tiles 0..14, staging tile tt+1 (unit u(tt,q) at phase q).
  // FIFO per wave: WAITV(4)@p1 retires u(tt-1,2..3) (cur kh1);
  //                WAITV(4)@p3 retires u(tt,0..1)   (next kh0).
  for (int tt = 0; tt < 15; ++tt) {
    const int c = tt & 1, cn = c ^ 1;
    const int kb = (tt + 1) * BK;

    // p0: kh0, n-frags 0,1  (reads confirmed at prev tile's p3 wait+barrier)
    LOADA(c, 0);
    LOADB2(c, 0, 0);
    STAGE(0, cn, 0, kb);     // u(tt,0)
    BARRIER();
    MFMA2(0);
    BARRIER();

    // p1: kh0, n-frags 2,3 (a[] reused)
    LOADB2(c, 0, 2);
    STAGE(1, cn, 0, kb);     // u(tt,1)
    WAITV(4);                // retire u(tt-1,2..3): kh1 of tile tt complete
    BARRIER();
    MFMA2(2);
    BARRIER();

    // p2: kh1, n-frags 0,1
    LOADA(c, 1);
    LOADB2(c, 1, 0);
    STAGE(0, cn, 1, kb);     // u(tt,2)
    BARRIER();
    MFMA2(0);
    BARRIER();

    // p3: kh1, n-frags 2,3
    LOADB2(c, 1, 2);
    STAGE(1, cn, 1, kb);     // u(tt,3)
    WAITV(4);                // retire u(tt,0..1): kh0 of tile tt+1 complete
    BARRIER();
    MFMA2(2);
    BARRIER();
  }

  // tail: tile 15 (buffer 1); outstanding at entry = u(14,2..3)
  LOADA(1, 0);
  LOADB2(1, 0, 0);
  BARRIER();
  MFMA2(0);
  BARRIER();

  LOADB2(1, 0, 2);
  WAITV(0);                  // retire u(14,2..3): kh1 of tile 15 complete
  BARRIER();
  MFMA2(2);
  BARRIER();

  LOADA(1, 1);
  LOADB2(1, 1, 0);
  BARRIER();
  MFMA2(0);
  BARRIER();

  LOADB2(1, 1, 2);
  BARRIER();
  MFMA2(2);

  // epilogue: C/D layout col = lane&15, row = (lane>>4)*4 + reg
  const int colg = lane & 15;
  const int rq = (lane >> 4) * 4;
#pragma unroll
  for (int j = 0; j < 4; ++j) {
    const int n = n0 + wn * 64 + j * 16 + colg;
    const float bv = bias[n];
#pragma unroll
    for (int i = 0; i < 8; ++i) {
      const size_t mb = (size_t)(m0 + wm * 128 + i * 16 + rq);
#pragma unroll
      for (int r = 0; r < 4; ++r)
        out[(mb + r) * N_DIM + n] = acc[i][j][r] + bv;
    }
  }
#undef STAGE
#undef LOADA
#undef LOADB2
#undef MFMA2
#undef WAITV
#undef BARRIER
}

// ---------------------------------------------------------------------------
// Fallback GEMM: round-1-verified 128^2 m97-structure kernel.
// ---------------------------------------------------------------------------
#define FBM 128
#define FBN 128
#define FBK 32
template <bool PRECONV>
__global__ __launch_bounds__(256) void gemm128(
    const bf16_t* __restrict__ Xh,
    const float*  __restrict__ Xf,
    const bf16_t* __restrict__ W,
    const float*  __restrict__ bias,
    float* __restrict__ out)
{
  __shared__ bf16_t As[FBM * FBK];
  __shared__ bf16_t Bs[FBN * FBK];

  const int rawbid = blockIdx.x;
  const int nblk = (M_DIM / FBM) * (N_DIM / FBN);   // 3072
  const int bid = (rawbid & 7) * (nblk / 8) + (rawbid >> 3);
  const int nt = bid % (N_DIM / FBN);
  const int mt = bid / (N_DIM / FBN);
  const int m0 = mt * FBM;
  const int n0 = nt * FBN;

  const int t = threadIdx.x;
  const int lane = t & 63;
  const int w = t >> 6;
  const int wm = w >> 1;
  const int wn = w & 1;

  const int r0 = t >> 2;
  const int c0 = (t & 3) * 8;

  const bf16_t* gB0 = W + (size_t)(n0 + r0) * K_DIM + c0;
  const bf16_t* gB1 = gB0 + (size_t)64 * K_DIM;
  bf16_t* lA0 = As + r0 * FBK + c0;
  bf16_t* lA1 = As + (r0 + 64) * FBK + c0;
  bf16_t* lB0 = Bs + r0 * FBK + c0;
  bf16_t* lB1 = Bs + (r0 + 64) * FBK + c0;

  const bf16_t* gA0h = nullptr; const bf16_t* gA1h = nullptr;
  const float*  gA0f = nullptr; const float*  gA1f = nullptr;
  if constexpr (PRECONV) {
    gA0h = Xh + (size_t)(m0 + r0) * K_DIM + c0;
    gA1h = gA0h + (size_t)64 * K_DIM;
  } else {
    gA0f = Xf + (size_t)(m0 + r0) * K_DIM + c0;
    gA1f = gA0f + (size_t)64 * K_DIM;
  }

  f32x4 acc[4][4];
#pragma unroll
  for (int i = 0; i < 4; ++i)
#pragma unroll
    for (int j = 0; j < 4; ++j) acc[i][j] = (f32x4){0.f, 0.f, 0.f, 0.f};

  const int row_a = wm * 64 + (lane & 15);
  const int row_b = wn * 64 + (lane & 15);
  const int kb = (lane >> 4) * 8;

  for (int k0 = 0; k0 < K_DIM; k0 += FBK) {
    if constexpr (PRECONV) {
      gload_lds16(gA0h + k0, lA0);
      gload_lds16(gA1h + k0, lA1);
    } else {
      const f32x4 u0 = *(const f32x4*)(gA0f + k0);
      const f32x4 u1 = *(const f32x4*)(gA0f + k0 + 4);
      const f32x4 u2 = *(const f32x4*)(gA1f + k0);
      const f32x4 u3 = *(const f32x4*)(gA1f + k0 + 4);
      bf16x8 a0, a1;
#pragma unroll
      for (int c = 0; c < 4; ++c) {
        a0[c] = (bf16_t)u0[c]; a0[c + 4] = (bf16_t)u1[c];
        a1[c] = (bf16_t)u2[c]; a1[c + 4] = (bf16_t)u3[c];
      }
      *(bf16x8*)lA0 = a0;
      *(bf16x8*)lA1 = a1;
    }
    gload_lds16(gB0 + k0, lB0);
    gload_lds16(gB1 + k0, lB1);
    __syncthreads();

    bf16x8 a[4], b[4];
#pragma unroll
    for (int i = 0; i < 4; ++i)
      a[i] = *(const bf16x8*)(As + (row_a + i * 16) * FBK + kb);
#pragma unroll
    for (int j = 0; j < 4; ++j)
      b[j] = *(const bf16x8*)(Bs + (row_b + j * 16) * FBK + kb);

#pragma unroll
    for (int i = 0; i < 4; ++i)
#pragma unroll
      for (int j = 0; j < 4; ++j)
        acc[i][j] = __builtin_amdgcn_mfma_f32_16x16x32_bf16(a[i], b[j], acc[i][j], 0, 0, 0);

    __syncthreads();
  }

  const int colg = lane & 15;
  const int rq = (lane >> 4) * 4;
#pragma unroll
  for (int j = 0; j < 4; ++j) {
    const int n = n0 + wn * 64 + j * 16 + colg;
    const float bv = bias[n];
#pragma unroll
    for (int i = 0; i < 4; ++i) {
      const size_t mb = (size_t)(m0 + wm * 64 + i * 16 + rq);
#pragma unroll
      for (int r = 0; r < 4; ++r)
        out[(mb + r) * N_DIM + n] = acc[i][j][r] + bv;
    }
  }
}

extern "C" void kernel_launch(void* const* d_in, const int* in_sizes, int n_in,
                              void* d_out, int out_size, void* d_ws, size_t ws_size,
                              hipStream_t stream) {
  const float* x      = (const float*)d_in[0];
  const float* base_w = (const float*)d_in[1];
  const float* base_b = (const float*)d_in[2];
  const float* vA     = (const float*)d_in[3];
  const float* vB     = (const float*)d_in[4];
  const float* vd     = (const float*)d_in[5];
  const float* vb     = (const float*)d_in[6];
  float* out = (float*)d_out;

  const size_t xh_off   = 8u * 1024 * 1024;
  const size_t xh_bytes = (size_t)M_DIM * K_DIM * sizeof(bf16_t);

  bf16_t* Wf = (bf16_t*)d_ws;
  const bool preconv = ws_size >= xh_off + xh_bytes;
  bf16_t* Xh = preconv ? (bf16_t*)((char*)d_ws + xh_off) : nullptr;

  // Raise the dynamic-LDS limit for the 128 KB kernel exactly once (host-side,
  // capture-safe). Falls back to the verified 128^2 kernel on failure.
  static int smem_ok = -1;
  if (smem_ok < 0) {
    hipError_t e = hipFuncSetAttribute(
        reinterpret_cast<const void*>(&gemm_qkv),
        hipFuncAttributeMaxDynamicSharedMemorySize, SMEM_BYTES);
    smem_ok = (e == hipSuccess) ? 1 : 0;
  }

  prep_all<<<preconv ? 8576 : 384, 256, 0, stream>>>(x, base_w, vA, vB, vd, vb, Wf, Xh);

  if (preconv && smem_ok == 1) {
    gemm_qkv<<<GRID_GEMM, 512, SMEM_BYTES, stream>>>(Xh, Wf, base_b, out);
  } else if (preconv) {
    gemm128<true><<<(M_DIM / FBM) * (N_DIM / FBN), 256, 0, stream>>>(
        Xh, nullptr, Wf, base_b, out);
  } else {
    gemm128<false><<<(M_DIM / FBM) * (N_DIM / FBN), 256, 0, stream>>>(
        nullptr, x, Wf, base_b, out);
  }
}

// Round 5
// 395.767 us; speedup vs baseline: 1.0438x; 1.0438x over previous
//
#include <hip/hip_runtime.h>
#include <hip/hip_bf16.h>
#include <cstdint>
#include <cstddef>

typedef __bf16 bf16_t;
typedef __bf16 bf16x8 __attribute__((ext_vector_type(8)));
typedef __bf16 bf16x4 __attribute__((ext_vector_type(4)));
typedef float  f32x4  __attribute__((ext_vector_type(4)));
typedef float  f32x16 __attribute__((ext_vector_type(16)));

#define M_DIM 16384   // B*S
#define N_DIM 3072    // 3*O
#define K_DIM 1024    // I
#define R_DIM 256
#define O_DIM 1024

// 256^2 8-phase geometry
#define BM 256
#define BN 256
#define BK 64
#define NTILE (N_DIM / BN)                    // 12
#define GRID_GEMM ((M_DIM / BM) * NTILE)      // 768
#define CHUNK_XCD (GRID_GEMM / 8)             // 96 (768 % 8 == 0 -> bijective)
#define SMEM_BYTES 131072

// LDS region map (bf16 elems): [c][A/B][kh] -> 256 rows x 32 k, 16 KB each.
#define REGN(c, isB, kh) ((c) * 32768 + (isB) * 16384 + (kh) * 8192)

__device__ __forceinline__ void gload_lds16(const bf16_t* g, bf16_t* l) {
  __builtin_amdgcn_global_load_lds(
      (__attribute__((address_space(1))) void*)(g),
      (__attribute__((address_space(3))) void*)(l), 16, 0, 0);
}

// ---------------------------------------------------------------------------
// prep: blocks [0,128): Q-rows fp32->bf16; [128,384): VeRA delta rows;
//       [384,8576): x fp32 -> bf16  (unchanged, verified rounds 0-4)
// ---------------------------------------------------------------------------
__global__ __launch_bounds__(256) void prep_all(
    const float* __restrict__ x,
    const float* __restrict__ base_w,
    const float* __restrict__ vA,
    const float* __restrict__ vB,
    const float* __restrict__ vd,
    const float* __restrict__ vb,
    bf16_t* __restrict__ Wf,
    bf16_t* __restrict__ xh)
{
  const int blk = blockIdx.x;
  const int t = threadIdx.x;

  if (blk >= 384) {
    const size_t base = ((size_t)(blk - 384) * 256 + t) * 8;
    const f32x4 v0 = *(const f32x4*)(x + base);
    const f32x4 v1 = *(const f32x4*)(x + base + 4);
    bf16x8 o;
    o[0] = (bf16_t)v0[0]; o[1] = (bf16_t)v0[1]; o[2] = (bf16_t)v0[2]; o[3] = (bf16_t)v0[3];
    o[4] = (bf16_t)v1[0]; o[5] = (bf16_t)v1[1]; o[6] = (bf16_t)v1[2]; o[7] = (bf16_t)v1[3];
    *(bf16x8*)(xh + base) = o;
    return;
  }

  if (blk < 128) {
    const float* src = base_w + (size_t)blk * 8 * K_DIM;
    bf16_t*      dst = Wf + (size_t)blk * 8 * K_DIM;
#pragma unroll
    for (int rr = 0; rr < 8; ++rr) {
      const f32x4 v = *(const f32x4*)(src + rr * K_DIM + t * 4);
      bf16x4 ov;
      ov[0] = (bf16_t)v[0]; ov[1] = (bf16_t)v[1];
      ov[2] = (bf16_t)v[2]; ov[3] = (bf16_t)v[3];
      *(bf16x4*)(dst + rr * K_DIM + t * 4) = ov;
    }
    return;
  }

  const int rb = (blk - 128) * 8;
  const int k  = rb >> 10;
  const int ob = rb & 1023;

  __shared__ float coeffT[R_DIM][8];
  {
    const int r = t;
    const float d = vd[k * R_DIM + r];
#pragma unroll
    for (int rr = 0; rr < 8; ++rr) {
      const int o = ob + rr;
      coeffT[r][rr] = vb[k * O_DIM + o] * vB[(size_t)o * R_DIM + r] * d;
    }
  }
  __syncthreads();

  float acc[8][4];
#pragma unroll
  for (int rr = 0; rr < 8; ++rr)
#pragma unroll
    for (int c = 0; c < 4; ++c) acc[rr][c] = 0.0f;

  for (int r = 0; r < R_DIM; ++r) {
    const f32x4 av = *(const f32x4*)(vA + (size_t)r * K_DIM + t * 4);
    const f32x4 c0 = *(const f32x4*)&coeffT[r][0];
    const f32x4 c1 = *(const f32x4*)&coeffT[r][4];
#pragma unroll
    for (int rr = 0; rr < 8; ++rr) {
      const float cc = (rr < 4) ? c0[rr] : c1[rr - 4];
      acc[rr][0] += cc * av[0];
      acc[rr][1] += cc * av[1];
      acc[rr][2] += cc * av[2];
      acc[rr][3] += cc * av[3];
    }
  }

#pragma unroll
  for (int rr = 0; rr < 8; ++rr) {
    const size_t row = (size_t)(1024 + rb + rr);
    const f32x4 bw = *(const f32x4*)(base_w + row * K_DIM + t * 4);
    bf16x4 ov;
    ov[0] = (bf16_t)(bw[0] + acc[rr][0]);
    ov[1] = (bf16_t)(bw[1] + acc[rr][1]);
    ov[2] = (bf16_t)(bw[2] + acc[rr][2]);
    ov[3] = (bf16_t)(bw[3] + acc[rr][3]);
    *(bf16x4*)(Wf + row * K_DIM + t * 4) = ov;
  }
}

// ---------------------------------------------------------------------------
// 256^2 8-phase GEMM with 32x32x16 MFMA (2495 TF ceiling vs 2176 for 16x16;
// half the MFMA instruction count). Phase machinery, vmcnt discipline and
// staging identical to the round-4 passing kernel.
// Fragments: A/B own-row = lane&31, k = (lane>>5)*8 (16B ds_read_b128);
// C/D: col = lane&31, row = (reg&3) + 8*(reg>>2) + 4*(lane>>5)  [m74/m101].
// ---------------------------------------------------------------------------
__global__ __launch_bounds__(512, 2) void gemm_qkv(
    const bf16_t* __restrict__ Xh,    // (16384, 1024) bf16
    const bf16_t* __restrict__ W,     // (3072, 1024)  bf16 row-major (N,K)
    const float*  __restrict__ bias,  // (3072,) fp32
    float* __restrict__ out)          // (16384, 3072) fp32
{
  extern __shared__ __align__(16) bf16_t sm[];  // 128 KB dynamic

  const int rawbid = blockIdx.x;
  const int bid = (rawbid & 7) * CHUNK_XCD + (rawbid >> 3);
  const int mt = bid / NTILE, nt = bid % NTILE;
  const int m0 = mt * BM, n0 = nt * BN;

  const int t = threadIdx.x;
  const int lane = t & 63;
  const int w = t >> 6;          // 0..7
  const int wm = w >> 2;         // 0..1 (M half)
  const int wn = w & 3;          // 0..3 (N quarter)

  // staging: thread t loads rows (t>>2), (t>>2)+128; 16B at pre-swizzled
  // k-slot sig = (t&3) ^ ((t>>3)&3). LDS dest linear: elem 8t per region.
  // => LDS[row][p] = G[row][p ^ ((row>>1)&3)]
  const int srow = t >> 2;
  const int sig  = (t & 3) ^ ((t >> 3) & 3);
  const bf16_t* pA0 = Xh + (size_t)(m0 + srow) * K_DIM + sig * 8;
  const bf16_t* pA1 = pA0 + (size_t)128 * K_DIM;
  const bf16_t* pB0 = W  + (size_t)(n0 + srow) * K_DIM + sig * 8;
  const bf16_t* pB1 = pB0 + (size_t)128 * K_DIM;

  // fragment read offsets (elems, region-local), row stride 32 elems.
  // row = frag_base + (lane&31); frag_base % 32 == 0 so (row>>1)&3 is
  // lane-only. To read global 16B-slot q: LDS slot = q ^ swz.
  // q = ks*2 + hi  (ks = k16-step in kh, hi = lane>>5).
  const int l31 = lane & 31;
  const int hi  = lane >> 5;
  const int swz = (l31 >> 1) & 3;
  const int sA  = (wm * 128 + l31) * 32;   // A frag row base (i-stride 1024)
  const int sB  = (wn * 64  + l31) * 32;   // B frag row base (j-stride 1024)
  const int sl0 = ((0 + hi) ^ swz) * 8;    // ks=0 slot offset (elems)
  const int sl1 = ((2 + hi) ^ swz) * 8;    // ks=1 slot offset

  f32x16 acc[4][2];
#pragma unroll
  for (int i = 0; i < 4; ++i)
#pragma unroll
    for (int j = 0; j < 2; ++j) acc[i][j] = (f32x16)0.0f;

#define STAGE(isB, c, kh, kb)                                              \
  do {                                                                     \
    const bf16_t* g0 = ((isB) ? pB0 : pA0) + (kb) + (kh) * 32;             \
    const bf16_t* g1 = ((isB) ? pB1 : pA1) + (kb) + (kh) * 32;             \
    bf16_t* l = sm + REGN(c, isB, kh) + w * 512;                           \
    gload_lds16(g0, l);                                                    \
    gload_lds16(g1, l + 4096);                                             \
  } while (0)

#define LOADA(c, kh)                                                       \
  {                                                                        \
    const bf16_t* base_ = sm + REGN(c, 0, kh) + sA;                        \
    _Pragma("unroll") for (int i = 0; i < 4; ++i) {                        \
      a[i][0] = *(const bf16x8*)(base_ + i * 1024 + sl0);                  \
      a[i][1] = *(const bf16x8*)(base_ + i * 1024 + sl1);                  \
    }                                                                      \
  }

#define LOADB(c, kh, j)                                                    \
  {                                                                        \
    const bf16_t* base_ = sm + REGN(c, 1, kh) + sB + (j) * 1024;           \
    b[j][0] = *(const bf16x8*)(base_ + sl0);                               \
    b[j][1] = *(const bf16x8*)(base_ + sl1);                               \
  }

#define MFMA8(j)                                                           \
  __builtin_amdgcn_s_setprio(1);                                           \
  _Pragma("unroll") for (int ks = 0; ks < 2; ++ks)                         \
    _Pragma("unroll") for (int i = 0; i < 4; ++i)                          \
      acc[i][j] = __builtin_amdgcn_mfma_f32_32x32x16_bf16(                 \
          a[i][ks], b[j][ks], acc[i][j], 0, 0, 0);                         \
  __builtin_amdgcn_s_setprio(0);

#define WAITV(n) asm volatile("s_waitcnt vmcnt(" #n ")" ::: "memory")
#define BARRIER()                                                          \
  __builtin_amdgcn_s_barrier();                                            \
  asm volatile("" ::: "memory")

  bf16x8 a[4][2], b[2][2];

  // prologue: stage tile 0 (units s0=A.kh0, s1=B.kh0, s2=A.kh1, s3=B.kh1)
  STAGE(0, 0, 0, 0);
  STAGE(1, 0, 0, 0);
  STAGE(0, 0, 1, 0);
  STAGE(1, 0, 1, 0);
  WAITV(4);     // retire s0,s1 -> kh0 of tile 0 complete (own wave)
  BARRIER();    // publish; s2,s3 still in flight

  // main loop: tiles 0..14, staging tile tt+1 (unit u(tt,q) at phase q).
  // FIFO per wave: WAITV(4)@p1 retires u(tt-1,2..3) (cur kh1);
  //                WAITV(4)@p3 retires u(tt,0..1)   (next kh0).
  for (int tt = 0; tt < 15; ++tt) {
    const int c = tt & 1, cn = c ^ 1;
    const int kb = (tt + 1) * BK;

    // p0: kh0, n-frag 0
    LOADA(c, 0);
    LOADB(c, 0, 0);
    STAGE(0, cn, 0, kb);     // u(tt,0)
    BARRIER();
    MFMA8(0);
    BARRIER();

    // p1: kh0, n-frag 1 (a[] reused)
    LOADB(c, 0, 1);
    STAGE(1, cn, 0, kb);     // u(tt,1)
    WAITV(4);                // retire u(tt-1,2..3): kh1 of tile tt complete
    BARRIER();
    MFMA8(1);
    BARRIER();

    // p2: kh1, n-frag 0
    LOADA(c, 1);
    LOADB(c, 1, 0);
    STAGE(0, cn, 1, kb);     // u(tt,2)
    BARRIER();
    MFMA8(0);
    BARRIER();

    // p3: kh1, n-frag 1
    LOADB(c, 1, 1);
    STAGE(1, cn, 1, kb);     // u(tt,3)
    WAITV(4);                // retire u(tt,0..1): kh0 of tile tt+1 complete
    BARRIER();
    MFMA8(1);
    BARRIER();
  }

  // tail: tile 15 (buffer 1); outstanding at entry = u(14,2..3)
  LOADA(1, 0);
  LOADB(1, 0, 0);
  BARRIER();
  MFMA8(0);
  BARRIER();

  LOADB(1, 0, 1);
  WAITV(0);                  // retire u(14,2..3): kh1 of tile 15 complete
  BARRIER();
  MFMA8(1);
  BARRIER();

  LOADA(1, 1);
  LOADB(1, 1, 0);
  BARRIER();
  MFMA8(0);
  BARRIER();

  LOADB(1, 1, 1);
  BARRIER();
  MFMA8(1);

  // epilogue: C/D col = lane&31 (n), row = (reg&3)+8*(reg>>2)+4*(lane>>5)
  const int hi4 = hi * 4;
#pragma unroll
  for (int j = 0; j < 2; ++j) {
    const int n = n0 + wn * 64 + j * 32 + l31;
    const float bv = bias[n];
#pragma unroll
    for (int i = 0; i < 4; ++i) {
      const size_t mb = (size_t)(m0 + wm * 128 + i * 32 + hi4);
#pragma unroll
      for (int r = 0; r < 16; ++r) {
        const size_t row = mb + (r & 3) + 8 * (r >> 2);
        out[row * N_DIM + n] = acc[i][j][r] + bv;
      }
    }
  }
#undef STAGE
#undef LOADA
#undef LOADB
#undef MFMA8
#undef WAITV
#undef BARRIER
}

// ---------------------------------------------------------------------------
// Fallback GEMM: round-1-verified 128^2 m97-structure kernel (16x16 MFMA).
// ---------------------------------------------------------------------------
#define FBM 128
#define FBN 128
#define FBK 32
template <bool PRECONV>
__global__ __launch_bounds__(256) void gemm128(
    const bf16_t* __restrict__ Xh,
    const float*  __restrict__ Xf,
    const bf16_t* __restrict__ W,
    const float*  __restrict__ bias,
    float* __restrict__ out)
{
  __shared__ bf16_t As[FBM * FBK];
  __shared__ bf16_t Bs[FBN * FBK];

  const int rawbid = blockIdx.x;
  const int nblk = (M_DIM / FBM) * (N_DIM / FBN);   // 3072
  const int bid = (rawbid & 7) * (nblk / 8) + (rawbid >> 3);
  const int nt = bid % (N_DIM / FBN);
  const int mt = bid / (N_DIM / FBN);
  const int m0 = mt * FBM;
  const int n0 = nt * FBN;

  const int t = threadIdx.x;
  const int lane = t & 63;
  const int w = t >> 6;
  const int wm = w >> 1;
  const int wn = w & 1;

  const int r0 = t >> 2;
  const int c0 = (t & 3) * 8;

  const bf16_t* gB0 = W + (size_t)(n0 + r0) * K_DIM + c0;
  const bf16_t* gB1 = gB0 + (size_t)64 * K_DIM;
  bf16_t* lA0 = As + r0 * FBK + c0;
  bf16_t* lA1 = As + (r0 + 64) * FBK + c0;
  bf16_t* lB0 = Bs + r0 * FBK + c0;
  bf16_t* lB1 = Bs + (r0 + 64) * FBK + c0;

  const bf16_t* gA0h = nullptr; const bf16_t* gA1h = nullptr;
  const float*  gA0f = nullptr; const float*  gA1f = nullptr;
  if constexpr (PRECONV) {
    gA0h = Xh + (size_t)(m0 + r0) * K_DIM + c0;
    gA1h = gA0h + (size_t)64 * K_DIM;
  } else {
    gA0f = Xf + (size_t)(m0 + r0) * K_DIM + c0;
    gA1f = gA0f + (size_t)64 * K_DIM;
  }

  f32x4 acc[4][4];
#pragma unroll
  for (int i = 0; i < 4; ++i)
#pragma unroll
    for (int j = 0; j < 4; ++j) acc[i][j] = (f32x4){0.f, 0.f, 0.f, 0.f};

  const int row_a = wm * 64 + (lane & 15);
  const int row_b = wn * 64 + (lane & 15);
  const int kb = (lane >> 4) * 8;

  for (int k0 = 0; k0 < K_DIM; k0 += FBK) {
    if constexpr (PRECONV) {
      gload_lds16(gA0h + k0, lA0);
      gload_lds16(gA1h + k0, lA1);
    } else {
      const f32x4 u0 = *(const f32x4*)(gA0f + k0);
      const f32x4 u1 = *(const f32x4*)(gA0f + k0 + 4);
      const f32x4 u2 = *(const f32x4*)(gA1f + k0);
      const f32x4 u3 = *(const f32x4*)(gA1f + k0 + 4);
      bf16x8 a0, a1;
#pragma unroll
      for (int c = 0; c < 4; ++c) {
        a0[c] = (bf16_t)u0[c]; a0[c + 4] = (bf16_t)u1[c];
        a1[c] = (bf16_t)u2[c]; a1[c + 4] = (bf16_t)u3[c];
      }
      *(bf16x8*)lA0 = a0;
      *(bf16x8*)lA1 = a1;
    }
    gload_lds16(gB0 + k0, lB0);
    gload_lds16(gB1 + k0, lB1);
    __syncthreads();

    bf16x8 a[4], b[4];
#pragma unroll
    for (int i = 0; i < 4; ++i)
      a[i] = *(const bf16x8*)(As + (row_a + i * 16) * FBK + kb);
#pragma unroll
    for (int j = 0; j < 4; ++j)
      b[j] = *(const bf16x8*)(Bs + (row_b + j * 16) * FBK + kb);

#pragma unroll
    for (int i = 0; i < 4; ++i)
#pragma unroll
      for (int j = 0; j < 4; ++j)
        acc[i][j] = __builtin_amdgcn_mfma_f32_16x16x32_bf16(a[i], b[j], acc[i][j], 0, 0, 0);

    __syncthreads();
  }

  const int colg = lane & 15;
  const int rq = (lane >> 4) * 4;
#pragma unroll
  for (int j = 0; j < 4; ++j) {
    const int n = n0 + wn * 64 + j * 16 + colg;
    const float bv = bias[n];
#pragma unroll
    for (int i = 0; i < 4; ++i) {
      const size_t mb = (size_t)(m0 + wm * 64 + i * 16 + rq);
#pragma unroll
      for (int r = 0; r < 4; ++r)
        out[(mb + r) * N_DIM + n] = acc[i][j][r] + bv;
    }
  }
}

extern "C" void kernel_launch(void* const* d_in, const int* in_sizes, int n_in,
                              void* d_out, int out_size, void* d_ws, size_t ws_size,
                              hipStream_t stream) {
  const float* x      = (const float*)d_in[0];
  const float* base_w = (const float*)d_in[1];
  const float* base_b = (const float*)d_in[2];
  const float* vA     = (const float*)d_in[3];
  const float* vB     = (const float*)d_in[4];
  const float* vd     = (const float*)d_in[5];
  const float* vb     = (const float*)d_in[6];
  float* out = (float*)d_out;

  const size_t xh_off   = 8u * 1024 * 1024;
  const size_t xh_bytes = (size_t)M_DIM * K_DIM * sizeof(bf16_t);

  bf16_t* Wf = (bf16_t*)d_ws;
  const bool preconv = ws_size >= xh_off + xh_bytes;
  bf16_t* Xh = preconv ? (bf16_t*)((char*)d_ws + xh_off) : nullptr;

  // Raise the dynamic-LDS limit for the 128 KB kernel exactly once (host-side,
  // capture-safe). Falls back to the verified 128^2 kernel on failure.
  static int smem_ok = -1;
  if (smem_ok < 0) {
    hipError_t e = hipFuncSetAttribute(
        reinterpret_cast<const void*>(&gemm_qkv),
        hipFuncAttributeMaxDynamicSharedMemorySize, SMEM_BYTES);
    smem_ok = (e == hipSuccess) ? 1 : 0;
  }

  prep_all<<<preconv ? 8576 : 384, 256, 0, stream>>>(x, base_w, vA, vB, vd, vb, Wf, Xh);

  if (preconv && smem_ok == 1) {
    gemm_qkv<<<GRID_GEMM, 512, SMEM_BYTES, stream>>>(Xh, Wf, base_b, out);
  } else if (preconv) {
    gemm128<true><<<(M_DIM / FBM) * (N_DIM / FBN), 256, 0, stream>>>(
        Xh, nullptr, Wf, base_b, out);
  } else {
    gemm128<false><<<(M_DIM / FBM) * (N_DIM / FBN), 256, 0, stream>>>(
        nullptr, x, Wf, base_b, out);
  }
}

// Round 6
// 389.229 us; speedup vs baseline: 1.0614x; 1.0168x over previous
//
#include <hip/hip_runtime.h>
#include <hip/hip_bf16.h>
#include <cstdint>
#include <cstddef>

typedef __bf16 bf16_t;
typedef __bf16 bf16x8 __attribute__((ext_vector_type(8)));
typedef __bf16 bf16x4 __attribute__((ext_vector_type(4)));
typedef float  f32x4  __attribute__((ext_vector_type(4)));
typedef float  f32x16 __attribute__((ext_vector_type(16)));

#define M_DIM 16384   // B*S
#define N_DIM 3072    // 3*O
#define K_DIM 1024    // I
#define R_DIM 256
#define O_DIM 1024

// 256^2 geometry
#define BM 256
#define BN 256
#define BK 64
#define NTILE (N_DIM / BN)                    // 12
#define GRID_GEMM ((M_DIM / BM) * NTILE)      // 768
#define CHUNK_XCD (GRID_GEMM / 8)             // 96 (768 % 8 == 0 -> bijective)
#define SMEM_BYTES 131072

// LDS region map (bf16 elems): [c][A/B][kh] -> 256 rows x 32 k, 16 KB each.
#define REGN(c, isB, kh) ((c) * 32768 + (isB) * 16384 + (kh) * 8192)

__device__ __forceinline__ void gload_lds16(const bf16_t* g, bf16_t* l) {
  __builtin_amdgcn_global_load_lds(
      (__attribute__((address_space(1))) void*)(g),
      (__attribute__((address_space(3))) void*)(l), 16, 0, 0);
}

// ---------------------------------------------------------------------------
// prep: blocks [0,128): Q-rows fp32->bf16; [128,384): VeRA delta rows;
//       [384,8576): x fp32 -> bf16  (unchanged, verified rounds 0-5)
// ---------------------------------------------------------------------------
__global__ __launch_bounds__(256) void prep_all(
    const float* __restrict__ x,
    const float* __restrict__ base_w,
    const float* __restrict__ vA,
    const float* __restrict__ vB,
    const float* __restrict__ vd,
    const float* __restrict__ vb,
    bf16_t* __restrict__ Wf,
    bf16_t* __restrict__ xh)
{
  const int blk = blockIdx.x;
  const int t = threadIdx.x;

  if (blk >= 384) {
    const size_t base = ((size_t)(blk - 384) * 256 + t) * 8;
    const f32x4 v0 = *(const f32x4*)(x + base);
    const f32x4 v1 = *(const f32x4*)(x + base + 4);
    bf16x8 o;
    o[0] = (bf16_t)v0[0]; o[1] = (bf16_t)v0[1]; o[2] = (bf16_t)v0[2]; o[3] = (bf16_t)v0[3];
    o[4] = (bf16_t)v1[0]; o[5] = (bf16_t)v1[1]; o[6] = (bf16_t)v1[2]; o[7] = (bf16_t)v1[3];
    *(bf16x8*)(xh + base) = o;
    return;
  }

  if (blk < 128) {
    const float* src = base_w + (size_t)blk * 8 * K_DIM;
    bf16_t*      dst = Wf + (size_t)blk * 8 * K_DIM;
#pragma unroll
    for (int rr = 0; rr < 8; ++rr) {
      const f32x4 v = *(const f32x4*)(src + rr * K_DIM + t * 4);
      bf16x4 ov;
      ov[0] = (bf16_t)v[0]; ov[1] = (bf16_t)v[1];
      ov[2] = (bf16_t)v[2]; ov[3] = (bf16_t)v[3];
      *(bf16x4*)(dst + rr * K_DIM + t * 4) = ov;
    }
    return;
  }

  const int rb = (blk - 128) * 8;
  const int k  = rb >> 10;
  const int ob = rb & 1023;

  __shared__ float coeffT[R_DIM][8];
  {
    const int r = t;
    const float d = vd[k * R_DIM + r];
#pragma unroll
    for (int rr = 0; rr < 8; ++rr) {
      const int o = ob + rr;
      coeffT[r][rr] = vb[k * O_DIM + o] * vB[(size_t)o * R_DIM + r] * d;
    }
  }
  __syncthreads();

  float acc[8][4];
#pragma unroll
  for (int rr = 0; rr < 8; ++rr)
#pragma unroll
    for (int c = 0; c < 4; ++c) acc[rr][c] = 0.0f;

  for (int r = 0; r < R_DIM; ++r) {
    const f32x4 av = *(const f32x4*)(vA + (size_t)r * K_DIM + t * 4);
    const f32x4 c0 = *(const f32x4*)&coeffT[r][0];
    const f32x4 c1 = *(const f32x4*)&coeffT[r][4];
#pragma unroll
    for (int rr = 0; rr < 8; ++rr) {
      const float cc = (rr < 4) ? c0[rr] : c1[rr - 4];
      acc[rr][0] += cc * av[0];
      acc[rr][1] += cc * av[1];
      acc[rr][2] += cc * av[2];
      acc[rr][3] += cc * av[3];
    }
  }

#pragma unroll
  for (int rr = 0; rr < 8; ++rr) {
    const size_t row = (size_t)(1024 + rb + rr);
    const f32x4 bw = *(const f32x4*)(base_w + row * K_DIM + t * 4);
    bf16x4 ov;
    ov[0] = (bf16_t)(bw[0] + acc[rr][0]);
    ov[1] = (bf16_t)(bw[1] + acc[rr][1]);
    ov[2] = (bf16_t)(bw[2] + acc[rr][2]);
    ov[3] = (bf16_t)(bw[3] + acc[rr][3]);
    *(bf16x4*)(Wf + row * K_DIM + t * 4) = ov;
  }
}

// ---------------------------------------------------------------------------
// 256^2 GEMM, 32x32x16 MFMA. Round-6 schedule: 4 single-barrier phases per
// K-tile, balanced by (kh, ks): each phase = {6 ds_read (4A+2B) || 1 stage
// unit || counted vmcnt; barrier; 8 MFMA}. Post-MFMA barriers dropped
// (WAR-audited: stages hit cn, reads hit c; boundary drift disjoint by kh).
// vmcnt: WAITV(4)@p1 retires [c][kh1] units; @p3 retires [cn][kh0] units.
// ---------------------------------------------------------------------------
__global__ __launch_bounds__(512, 2) void gemm_qkv(
    const bf16_t* __restrict__ Xh,    // (16384, 1024) bf16
    const bf16_t* __restrict__ W,     // (3072, 1024)  bf16 row-major (N,K)
    const float*  __restrict__ bias,  // (3072,) fp32
    float* __restrict__ out)          // (16384, 3072) fp32
{
  extern __shared__ __align__(16) bf16_t sm[];  // 128 KB dynamic

  const int rawbid = blockIdx.x;
  const int bid = (rawbid & 7) * CHUNK_XCD + (rawbid >> 3);
  const int mt = bid / NTILE, nt = bid % NTILE;
  const int m0 = mt * BM, n0 = nt * BN;

  const int t = threadIdx.x;
  const int lane = t & 63;
  const int w = t >> 6;          // 0..7
  const int wm = w >> 2;         // 0..1 (M half)
  const int wn = w & 3;          // 0..3 (N quarter)

  // staging: thread t loads rows (t>>2), (t>>2)+128; 16B at pre-swizzled
  // k-slot sig = (t&3) ^ ((t>>3)&3). LDS dest linear: elem 8t per region.
  // => LDS[row][p] = G[row][p ^ ((row>>1)&3)]
  const int srow = t >> 2;
  const int sig  = (t & 3) ^ ((t >> 3) & 3);
  const bf16_t* pA0 = Xh + (size_t)(m0 + srow) * K_DIM + sig * 8;
  const bf16_t* pA1 = pA0 + (size_t)128 * K_DIM;
  const bf16_t* pB0 = W  + (size_t)(n0 + srow) * K_DIM + sig * 8;
  const bf16_t* pB1 = pB0 + (size_t)128 * K_DIM;

  // fragment read offsets (elems, region-local), row stride 32 elems.
  // global 16B-slot q = ks*2 + hi; LDS slot = q ^ swz, swz = (l31>>1)&3.
  const int l31 = lane & 31;
  const int hi  = lane >> 5;
  const int swz = (l31 >> 1) & 3;
  const int sA  = (wm * 128 + l31) * 32;   // A frag row base (i-stride 1024)
  const int sB  = (wn * 64  + l31) * 32;   // B frag row base (j-stride 1024)
  const int sl0 = ((0 + hi) ^ swz) * 8;    // ks=0 slot offset (elems)
  const int sl1 = ((2 + hi) ^ swz) * 8;    // ks=1 slot offset

  f32x16 acc[4][2];
#pragma unroll
  for (int i = 0; i < 4; ++i)
#pragma unroll
    for (int j = 0; j < 2; ++j) acc[i][j] = (f32x16)0.0f;

#define STAGE(isB, c, kh, kb)                                              \
  do {                                                                     \
    const bf16_t* g0 = ((isB) ? pB0 : pA0) + (kb) + (kh) * 32;             \
    const bf16_t* g1 = ((isB) ? pB1 : pA1) + (kb) + (kh) * 32;             \
    bf16_t* l = sm + REGN(c, isB, kh) + w * 512;                           \
    gload_lds16(g0, l);                                                    \
    gload_lds16(g1, l + 4096);                                             \
  } while (0)

#define LOADA4(c, kh, ks)                                                  \
  {                                                                        \
    const bf16_t* base_ = sm + REGN(c, 0, kh) + sA + ((ks) ? sl1 : sl0);   \
    _Pragma("unroll") for (int i = 0; i < 4; ++i)                          \
        a[i] = *(const bf16x8*)(base_ + i * 1024);                         \
  }

#define LOADB2(c, kh, ks)                                                  \
  {                                                                        \
    const bf16_t* base_ = sm + REGN(c, 1, kh) + sB + ((ks) ? sl1 : sl0);   \
    b[0] = *(const bf16x8*)(base_);                                        \
    b[1] = *(const bf16x8*)(base_ + 1024);                                 \
  }

#define MFMA8()                                                            \
  __builtin_amdgcn_s_setprio(1);                                           \
  _Pragma("unroll") for (int i = 0; i < 4; ++i)                            \
    _Pragma("unroll") for (int j = 0; j < 2; ++j)                          \
      acc[i][j] = __builtin_amdgcn_mfma_f32_32x32x16_bf16(                 \
          a[i], b[j], acc[i][j], 0, 0, 0);                                 \
  __builtin_amdgcn_s_setprio(0);

#define WAITV(n) asm volatile("s_waitcnt vmcnt(" #n ")" ::: "memory")
#define BARRIER()                                                          \
  __builtin_amdgcn_s_barrier();                                            \
  asm volatile("" ::: "memory")

  bf16x8 a[4], b[2];

  // prologue: stage tile 0 (units s0=A.kh0, s1=B.kh0, s2=A.kh1, s3=B.kh1)
  STAGE(0, 0, 0, 0);
  STAGE(1, 0, 0, 0);
  STAGE(0, 0, 1, 0);
  STAGE(1, 0, 1, 0);
  WAITV(4);     // retire s0,s1 -> [0][kh0] complete (own wave)
  BARRIER();    // publish; s2,s3 still in flight

  // main loop: tiles 0..14, staging tile tt+1 one unit per phase.
  // In-flight at p1 wait: {prev kh1 pair, cur-staged 2} = 8 -> WAITV(4)
  // retires prev kh1 (read at p2/p3). At p3: {u(tt,0..3)} = 8 -> WAITV(4)
  // retires u(tt,0..1) = [cn][kh0] (read at next tile p0/p1).
  for (int tt = 0; tt < 15; ++tt) {
    const int c = tt & 1, cn = c ^ 1;
    const int kb = (tt + 1) * BK;

    // p0: kh0, ks0
    LOADA4(c, 0, 0);
    LOADB2(c, 0, 0);
    STAGE(0, cn, 0, kb);     // u(tt,0) = A[cn][kh0]
    BARRIER();
    MFMA8();

    // p1: kh0, ks1
    LOADA4(c, 0, 1);
    LOADB2(c, 0, 1);
    STAGE(1, cn, 0, kb);     // u(tt,1) = B[cn][kh0]
    WAITV(4);                // confirm [c][kh1]
    BARRIER();
    MFMA8();

    // p2: kh1, ks0
    LOADA4(c, 1, 0);
    LOADB2(c, 1, 0);
    STAGE(0, cn, 1, kb);     // u(tt,2) = A[cn][kh1]
    BARRIER();
    MFMA8();

    // p3: kh1, ks1
    LOADA4(c, 1, 1);
    LOADB2(c, 1, 1);
    STAGE(1, cn, 1, kb);     // u(tt,3) = B[cn][kh1]
    WAITV(4);                // confirm [cn][kh0] for next tile
    BARRIER();
    MFMA8();
  }

  // tail: tile 15 (buffer 1); outstanding at entry = u(14,2..3) (4 loads).
  // kh0 confirmed at tile14.p3; kh1 confirmed by WAITV(0) at t-p1.
  LOADA4(1, 0, 0);
  LOADB2(1, 0, 0);
  BARRIER();
  MFMA8();

  LOADA4(1, 0, 1);
  LOADB2(1, 0, 1);
  WAITV(0);                  // retire u(14,2..3): [1][kh1] complete
  BARRIER();
  MFMA8();

  LOADA4(1, 1, 0);
  LOADB2(1, 1, 0);
  BARRIER();
  MFMA8();

  LOADA4(1, 1, 1);
  LOADB2(1, 1, 1);
  BARRIER();
  MFMA8();

  // epilogue: C/D col = lane&31 (n), row = (reg&3)+8*(reg>>2)+4*(lane>>5)
  const int hi4 = hi * 4;
#pragma unroll
  for (int j = 0; j < 2; ++j) {
    const int n = n0 + wn * 64 + j * 32 + l31;
    const float bv = bias[n];
#pragma unroll
    for (int i = 0; i < 4; ++i) {
      const size_t mb = (size_t)(m0 + wm * 128 + i * 32 + hi4);
#pragma unroll
      for (int r = 0; r < 16; ++r) {
        const size_t row = mb + (r & 3) + 8 * (r >> 2);
        out[row * N_DIM + n] = acc[i][j][r] + bv;
      }
    }
  }
#undef STAGE
#undef LOADA4
#undef LOADB2
#undef MFMA8
#undef WAITV
#undef BARRIER
}

// ---------------------------------------------------------------------------
// Fallback GEMM: round-1-verified 128^2 m97-structure kernel (16x16 MFMA).
// ---------------------------------------------------------------------------
#define FBM 128
#define FBN 128
#define FBK 32
template <bool PRECONV>
__global__ __launch_bounds__(256) void gemm128(
    const bf16_t* __restrict__ Xh,
    const float*  __restrict__ Xf,
    const bf16_t* __restrict__ W,
    const float*  __restrict__ bias,
    float* __restrict__ out)
{
  __shared__ bf16_t As[FBM * FBK];
  __shared__ bf16_t Bs[FBN * FBK];

  const int rawbid = blockIdx.x;
  const int nblk = (M_DIM / FBM) * (N_DIM / FBN);   // 3072
  const int bid = (rawbid & 7) * (nblk / 8) + (rawbid >> 3);
  const int nt = bid % (N_DIM / FBN);
  const int mt = bid / (N_DIM / FBN);
  const int m0 = mt * FBM;
  const int n0 = nt * FBN;

  const int t = threadIdx.x;
  const int lane = t & 63;
  const int w = t >> 6;
  const int wm = w >> 1;
  const int wn = w & 1;

  const int r0 = t >> 2;
  const int c0 = (t & 3) * 8;

  const bf16_t* gB0 = W + (size_t)(n0 + r0) * K_DIM + c0;
  const bf16_t* gB1 = gB0 + (size_t)64 * K_DIM;
  bf16_t* lA0 = As + r0 * FBK + c0;
  bf16_t* lA1 = As + (r0 + 64) * FBK + c0;
  bf16_t* lB0 = Bs + r0 * FBK + c0;
  bf16_t* lB1 = Bs + (r0 + 64) * FBK + c0;

  const bf16_t* gA0h = nullptr; const bf16_t* gA1h = nullptr;
  const float*  gA0f = nullptr; const float*  gA1f = nullptr;
  if constexpr (PRECONV) {
    gA0h = Xh + (size_t)(m0 + r0) * K_DIM + c0;
    gA1h = gA0h + (size_t)64 * K_DIM;
  } else {
    gA0f = Xf + (size_t)(m0 + r0) * K_DIM + c0;
    gA1f = gA0f + (size_t)64 * K_DIM;
  }

  f32x4 acc[4][4];
#pragma unroll
  for (int i = 0; i < 4; ++i)
#pragma unroll
    for (int j = 0; j < 4; ++j) acc[i][j] = (f32x4){0.f, 0.f, 0.f, 0.f};

  const int row_a = wm * 64 + (lane & 15);
  const int row_b = wn * 64 + (lane & 15);
  const int kb = (lane >> 4) * 8;

  for (int k0 = 0; k0 < K_DIM; k0 += FBK) {
    if constexpr (PRECONV) {
      gload_lds16(gA0h + k0, lA0);
      gload_lds16(gA1h + k0, lA1);
    } else {
      const f32x4 u0 = *(const f32x4*)(gA0f + k0);
      const f32x4 u1 = *(const f32x4*)(gA0f + k0 + 4);
      const f32x4 u2 = *(const f32x4*)(gA1f + k0);
      const f32x4 u3 = *(const f32x4*)(gA1f + k0 + 4);
      bf16x8 a0, a1;
#pragma unroll
      for (int c = 0; c < 4; ++c) {
        a0[c] = (bf16_t)u0[c]; a0[c + 4] = (bf16_t)u1[c];
        a1[c] = (bf16_t)u2[c]; a1[c + 4] = (bf16_t)u3[c];
      }
      *(bf16x8*)lA0 = a0;
      *(bf16x8*)lA1 = a1;
    }
    gload_lds16(gB0 + k0, lB0);
    gload_lds16(gB1 + k0, lB1);
    __syncthreads();

    bf16x8 a[4], b[4];
#pragma unroll
    for (int i = 0; i < 4; ++i)
      a[i] = *(const bf16x8*)(As + (row_a + i * 16) * FBK + kb);
#pragma unroll
    for (int j = 0; j < 4; ++j)
      b[j] = *(const bf16x8*)(Bs + (row_b + j * 16) * FBK + kb);

#pragma unroll
    for (int i = 0; i < 4; ++i)
#pragma unroll
      for (int j = 0; j < 4; ++j)
        acc[i][j] = __builtin_amdgcn_mfma_f32_16x16x32_bf16(a[i], b[j], acc[i][j], 0, 0, 0);

    __syncthreads();
  }

  const int colg = lane & 15;
  const int rq = (lane >> 4) * 4;
#pragma unroll
  for (int j = 0; j < 4; ++j) {
    const int n = n0 + wn * 64 + j * 16 + colg;
    const float bv = bias[n];
#pragma unroll
    for (int i = 0; i < 4; ++i) {
      const size_t mb = (size_t)(m0 + wm * 64 + i * 16 + rq);
#pragma unroll
      for (int r = 0; r < 4; ++r)
        out[(mb + r) * N_DIM + n] = acc[i][j][r] + bv;
    }
  }
}

extern "C" void kernel_launch(void* const* d_in, const int* in_sizes, int n_in,
                              void* d_out, int out_size, void* d_ws, size_t ws_size,
                              hipStream_t stream) {
  const float* x      = (const float*)d_in[0];
  const float* base_w = (const float*)d_in[1];
  const float* base_b = (const float*)d_in[2];
  const float* vA     = (const float*)d_in[3];
  const float* vB     = (const float*)d_in[4];
  const float* vd     = (const float*)d_in[5];
  const float* vb     = (const float*)d_in[6];
  float* out = (float*)d_out;

  const size_t xh_off   = 8u * 1024 * 1024;
  const size_t xh_bytes = (size_t)M_DIM * K_DIM * sizeof(bf16_t);

  bf16_t* Wf = (bf16_t*)d_ws;
  const bool preconv = ws_size >= xh_off + xh_bytes;
  bf16_t* Xh = preconv ? (bf16_t*)((char*)d_ws + xh_off) : nullptr;

  // Raise the dynamic-LDS limit for the 128 KB kernel exactly once (host-side,
  // capture-safe). Falls back to the verified 128^2 kernel on failure.
  static int smem_ok = -1;
  if (smem_ok < 0) {
    hipError_t e = hipFuncSetAttribute(
        reinterpret_cast<const void*>(&gemm_qkv),
        hipFuncAttributeMaxDynamicSharedMemorySize, SMEM_BYTES);
    smem_ok = (e == hipSuccess) ? 1 : 0;
  }

  prep_all<<<preconv ? 8576 : 384, 256, 0, stream>>>(x, base_w, vA, vB, vd, vb, Wf, Xh);

  if (preconv && smem_ok == 1) {
    gemm_qkv<<<GRID_GEMM, 512, SMEM_BYTES, stream>>>(Xh, Wf, base_b, out);
  } else if (preconv) {
    gemm128<true><<<(M_DIM / FBM) * (N_DIM / FBN), 256, 0, stream>>>(
        Xh, nullptr, Wf, base_b, out);
  } else {
    gemm128<false><<<(M_DIM / FBM) * (N_DIM / FBN), 256, 0, stream>>>(
        nullptr, x, Wf, base_b, out);
  }
}